// Round 8
// baseline (2602.942 us; speedup 1.0000x reference)
//
#include <hip/hip_runtime.h>

// 2-layer LSTM (B=512, T=300, D=80, H=128) + FC head on MI355X.
// Round 8: producer/consumer pipeline (64 WGs) with x-part/h-part gate split.
//  - gates(t) = [bias + Wih*x(t)]  (precomputed in shadow of step t-1, off-path)
//             + [Whh*h(t-1)]       (4 dependent MFMAs, on-path)
//  - producer: counted vmcnt(5)/vmcnt(3) (never drains young ops on path);
//    monotone flag counter published by all waves after own-store guarantee.
//  - consumer: 2-deep LLC prefetch of h1; one free vmcnt(0)/step; shadow
//    builds acc_x(t+1) from h1(t+1) so LLC latency is off-path.

typedef _Float16 f16;
typedef _Float16 f16x8 __attribute__((ext_vector_type(8)));
typedef float f32x4 __attribute__((ext_vector_type(4)));
typedef unsigned u32x2 __attribute__((ext_vector_type(2)));

#define T_SEQ 300
#define D_IN  80
#define HDIM  128
#define B_ALL 512
#define B_TILE 16
#define N_PROD 32
#define N_WG_TOT 64

#define XT_BYTES  ((size_t)B_ALL * T_SEQ * D_IN * 2)   // 24,576,000
#define H1_BYTES  ((size_t)T_SEQ * B_ALL * HDIM * 2)   // 39,321,600
#define FLAGS_OFF (XT_BYTES + H1_BYTES)
#define FLAGS_BYTES ((size_t)N_PROD * 4)               // one counter per tile
#define HSTEP_BYTES ((uint64_t)B_ALL * HDIM * 2)       // 131072

__device__ __forceinline__ float sigm(float x) {
    return __builtin_amdgcn_rcpf(1.0f + __builtin_amdgcn_exp2f(-1.44269504f * x));
}
__device__ __forceinline__ float tanh_fast(float x) {
    return 1.0f - 2.0f * __builtin_amdgcn_rcpf(1.0f + __builtin_amdgcn_exp2f(2.88539008f * x));
}

__device__ __forceinline__ void wg_barrier_lds() {
    asm volatile("s_waitcnt lgkmcnt(0)" ::: "memory");
    __builtin_amdgcn_sched_barrier(0);
    __builtin_amdgcn_s_barrier();
    __builtin_amdgcn_sched_barrier(0);
}
__device__ __forceinline__ void vm_drain() {
    asm volatile("s_waitcnt vmcnt(0)" ::: "memory");
    __builtin_amdgcn_sched_barrier(0);
}

// ---------------- prep: x (B,D,T) f32 -> xT (B,T,80) f16
__global__ __launch_bounds__(256) void k_prep(const float* __restrict__ x,
                                              f16* __restrict__ xT) {
    __shared__ f16 tile[D_IN][T_SEQ + 8];
    const int b = blockIdx.x;
    const int tid = threadIdx.x;
    const float* xb = x + (size_t)b * D_IN * T_SEQ;
    for (int i = tid; i < D_IN * T_SEQ; i += 256) {
        int d = i / T_SEQ;
        int t = i - d * T_SEQ;
        tile[d][t] = (f16)xb[i];
    }
    __syncthreads();
    f16* outb = xT + (size_t)b * T_SEQ * D_IN;
    for (int i = tid; i < T_SEQ * (D_IN / 8); i += 256) {
        int t  = i / (D_IN / 8);
        int dc = i - t * (D_IN / 8);
        f16x8 v;
#pragma unroll
        for (int e = 0; e < 8; ++e) v[e] = tile[dc * 8 + e][t];
        *(f16x8*)(outb + t * D_IN + dc * 8) = v;
    }
}

__device__ __forceinline__ f16x8 load_wfrag(const float* __restrict__ W,
                                            int row, int ld, int k0, int kmax) {
    f16x8 v;
#pragma unroll
    for (int e = 0; e < 8; ++e) {
        int k = k0 + e;
        v[e] = (k < kmax) ? (f16)W[row * ld + k] : (f16)0.0f;
    }
    return v;
}

__global__ __launch_bounds__(512, 2) void k_lstm(
    const f16* __restrict__ xT, f16* __restrict__ h1ws, int* __restrict__ flags,
    const float* __restrict__ Wih0, const float* __restrict__ Whh0,
    const float* __restrict__ bih0, const float* __restrict__ bhh0,
    const float* __restrict__ Wih1, const float* __restrict__ Whh1,
    const float* __restrict__ bih1, const float* __restrict__ bhh1,
    const float* __restrict__ fc1w, const float* __restrict__ fc1b,
    const float* __restrict__ fc2w, const float* __restrict__ fc2b,
    const float* __restrict__ fc3w, const float* __restrict__ fc3b,
    float* __restrict__ out)
{
    const int tid = threadIdx.x;
    const int wv  = tid >> 6;
    const int l   = tid & 63;
    const int l16 = l & 15;
    const int lg  = l >> 4;
    const int wg  = blockIdx.x;
    const int u   = wv * 16 + l16;

    __shared__ __align__(16) f16 hbuf[2][16 * HDIM];
    __shared__ float h2buf[16][HDIM];
    __shared__ float a1buf[16][64];
    __shared__ float a2buf[16][33];

    for (int i = tid; i < 16 * HDIM; i += 512) hbuf[0][i] = (f16)0.0f;

    float cst[4] = {0.f, 0.f, 0.f, 0.f};

    if (wg < N_PROD) {
        // ===================== PRODUCER: layer 0 =====================
        const int wgb = wg;
        f16x8 wih[4][3], whh[4][4];
        float biasv[4];
#pragma unroll
        for (int nt = 0; nt < 4; ++nt) {
            int gate = nt * 128 + u;
            biasv[nt] = bih0[gate] + bhh0[gate];
#pragma unroll
            for (int kc = 0; kc < 4; ++kc)
                whh[nt][kc] = load_wfrag(Whh0, gate, HDIM, kc * 32 + lg * 8, HDIM);
#pragma unroll
            for (int kc = 0; kc < 3; ++kc)
                wih[nt][kc] = load_wfrag(Wih0, gate, D_IN, kc * 32 + lg * 8, D_IN);
        }

        const f16* xrowp = xT + (size_t)(wgb * B_TILE + l16) * T_SEQ * D_IN + lg * 8;
        const uint64_t xrowu = (uint64_t)(uintptr_t)xrowp;
        const uint64_t flagu = (uint64_t)(uintptr_t)(flags + wgb);
        // handoff-store geometry: thread -> (row sbr, 8 bytes at col-byte sob)
        const int sbr = tid >> 5;
        const int sob = (tid & 31) * 8;
        const int sswz = (((sob >> 4) ^ (sbr & 7)) << 4) + (sob & 8);
        const uint64_t sdst0 = (uint64_t)(uintptr_t)h1ws +
                               (uint64_t)(wgb * B_TILE + sbr) * 256 + sob;

        // prologue: plain loads of x(0), x(1); acc_x(0) = bias + Wih*x(0)
        f16x8 p0 = *(const f16x8*)(xrowp);
        f16x8 p1 = *(const f16x8*)(xrowp + 32);
        f16x8 p2 = *(const f16x8*)(xrowp + 64);
        f16x8 xA0 = *(const f16x8*)(xrowp + D_IN);
        f16x8 xA1 = *(const f16x8*)(xrowp + D_IN + 32);
        f16x8 xA2 = *(const f16x8*)(xrowp + D_IN + 64);
        f32x4 acc_x[4];
#pragma unroll
        for (int nt = 0; nt < 4; ++nt) {
            f32x4 a = {biasv[nt], biasv[nt], biasv[nt], biasv[nt]};
            a = __builtin_amdgcn_mfma_f32_16x16x32_f16(p0, wih[nt][0], a, 0, 0, 0);
            a = __builtin_amdgcn_mfma_f32_16x16x32_f16(p1, wih[nt][1], a, 0, 0, 0);
            a = __builtin_amdgcn_mfma_f32_16x16x32_f16(p2, wih[nt][2], a, 0, 0, 0);
            acc_x[nt] = a;
        }
        __syncthreads();  // hbuf[0] zeros visible

        auto pstep = [&](int t, f16x8& xc0, f16x8& xc1, f16x8& xc2,
                         f16x8& xn0, f16x8& xn1, f16x8& xn2) {
            const f16* cur = hbuf[t & 1];
            f16* nxt = hbuf[(t + 1) & 1];
            // ha reads first (latency head start)
            f16x8 ha[4];
#pragma unroll
            for (int kc = 0; kc < 4; ++kc) {
                int chunk = kc * 4 + lg;
                ha[kc] = *(const f16x8*)(cur + l16 * HDIM + ((chunk ^ (l16 & 7)) << 3));
            }
            // handoff store h(t-1) (coalesced 8B/lane from LDS)
            if (t >= 1) {
                u32x2 hval = *(const u32x2*)((const char*)cur + sbr * 256 + sswz);
                uint64_t dst = sdst0 + (uint64_t)(t - 1) * HSTEP_BYTES;
                asm volatile("global_store_dwordx2 %0, %1, off sc0 sc1"
                             :: "v"(dst), "v"(hval) : "memory");
            }
            // x loads for t+2 (plain, L2-cached)
            {
                int tl = (t + 2 < T_SEQ) ? t + 2 : T_SEQ - 1;
                uint64_t xa = xrowu + (uint64_t)tl * (D_IN * 2);
                asm volatile("global_load_dwordx4 %0, %1, off"            : "=v"(xn0) : "v"(xa) : "memory");
                asm volatile("global_load_dwordx4 %0, %1, off offset:64"  : "=v"(xn1) : "v"(xa) : "memory");
                asm volatile("global_load_dwordx4 %0, %1, off offset:128" : "=v"(xn2) : "v"(xa) : "memory");
            }
            // path: 4 dependent h-MFMAs per gate, C-init = acc_x(t)
            f32x4 acc[4];
#pragma unroll
            for (int nt = 0; nt < 4; ++nt) {
                f32x4 a = acc_x[nt];
                a = __builtin_amdgcn_mfma_f32_16x16x32_f16(ha[0], whh[nt][0], a, 0, 0, 0);
                a = __builtin_amdgcn_mfma_f32_16x16x32_f16(ha[1], whh[nt][1], a, 0, 0, 0);
                a = __builtin_amdgcn_mfma_f32_16x16x32_f16(ha[2], whh[nt][2], a, 0, 0, 0);
                a = __builtin_amdgcn_mfma_f32_16x16x32_f16(ha[3], whh[nt][3], a, 0, 0, 0);
                acc[nt] = a;
            }
            // xcur (x(t+1), loaded at t-1) guaranteed by counted wait:
            // outstanding order: loads(t-1)[3], flag(t-1), hstore(t), loads(t)[3]
            asm volatile("s_waitcnt vmcnt(5)" ::: "memory");
            __builtin_amdgcn_sched_barrier(0);
            // shadow: rebuild acc_x for t+1 (off-path MFMAs)
#pragma unroll
            for (int nt = 0; nt < 4; ++nt) {
                f32x4 a = {biasv[nt], biasv[nt], biasv[nt], biasv[nt]};
                a = __builtin_amdgcn_mfma_f32_16x16x32_f16(xc0, wih[nt][0], a, 0, 0, 0);
                a = __builtin_amdgcn_mfma_f32_16x16x32_f16(xc1, wih[nt][1], a, 0, 0, 0);
                a = __builtin_amdgcn_mfma_f32_16x16x32_f16(xc2, wih[nt][2], a, 0, 0, 0);
                acc_x[nt] = a;
            }
            // activations (on-path) -> h(t) into LDS
#pragma unroll
            for (int r = 0; r < 4; ++r) {
                float iv = sigm(acc[0][r]);
                float fv = sigm(acc[1][r]);
                float gv = tanh_fast(acc[2][r]);
                float ov = sigm(acc[3][r]);
                float cn = fv * cst[r] + iv * gv;
                cst[r] = cn;
                f16 hh = (f16)(ov * tanh_fast(cn));
                int br = lg * 4 + r;
                nxt[br * HDIM + ((((unsigned)u >> 3) ^ (br & 7)) << 3) + (u & 7)] = hh;
            }
            // own h-store retired (3 newer loads) -> publish flag = t (h1[0..t-1])
            asm volatile("s_waitcnt vmcnt(3)" ::: "memory");
            __builtin_amdgcn_sched_barrier(0);
            if (l == 0) {
                unsigned cv = (unsigned)t;
                asm volatile("global_store_dword %0, %1, off sc0 sc1"
                             :: "v"(flagu), "v"(cv) : "memory");
            }
            wg_barrier_lds();
        };

        f16x8 xB0, xB1, xB2;
        for (int t = 0; t < T_SEQ; t += 2) {
            pstep(t,     xA0, xA1, xA2, xB0, xB1, xB2);
            pstep(t + 1, xB0, xB1, xB2, xA0, xA1, xA2);
        }
        // tail: store h(T-1) (in hbuf[T&1]) and publish flag = T
        {
            const f16* cur = hbuf[T_SEQ & 1];
            u32x2 hval = *(const u32x2*)((const char*)cur + sbr * 256 + sswz);
            uint64_t dst = sdst0 + (uint64_t)(T_SEQ - 1) * HSTEP_BYTES;
            asm volatile("global_store_dwordx2 %0, %1, off sc0 sc1"
                         :: "v"(dst), "v"(hval) : "memory");
            vm_drain();
            unsigned cv = (unsigned)T_SEQ;
            if (l == 0)
                asm volatile("global_store_dword %0, %1, off sc0 sc1"
                             :: "v"(flagu), "v"(cv) : "memory");
        }
        return;
    }

    // ===================== CONSUMER: layer 1 + FC =====================
    {
        const int wgb = wg - N_PROD;
        f16x8 wih[4][4], whh[4][4];
        float biasv[4];
#pragma unroll
        for (int nt = 0; nt < 4; ++nt) {
            int gate = nt * 128 + u;
            biasv[nt] = bih1[gate] + bhh1[gate];
#pragma unroll
            for (int kc = 0; kc < 4; ++kc) {
                wih[nt][kc] = load_wfrag(Wih1, gate, HDIM, kc * 32 + lg * 8, HDIM);
                whh[nt][kc] = load_wfrag(Whh1, gate, HDIM, kc * 32 + lg * 8, HDIM);
            }
        }
        __syncthreads();  // hbuf zeros visible

        const uint64_t flagu = (uint64_t)(uintptr_t)(flags + wgb);
        const uint64_t xbase = (uint64_t)(uintptr_t)h1ws +
                               (uint64_t)(wgb * B_TILE + l16) * 256 + (uint64_t)lg * 16;

        // prologue: wait flag >= 2 (h1[0], h1[1] ready)
        unsigned pv = 0;
        do {
            asm volatile("global_load_dword %0, %1, off sc0 sc1"
                         : "=v"(pv) : "v"(flagu) : "memory");
            asm volatile("s_waitcnt vmcnt(0)" ::: "memory");
        } while (pv < 2u);
        // load h1(0) -> q, h1(1) -> xA
        f16x8 q0, q1, q2, q3, xA0, xA1, xA2, xA3;
        {
            uint64_t a0 = xbase;
            asm volatile("global_load_dwordx4 %0, %1, off sc0 sc1"            : "=v"(q0) : "v"(a0) : "memory");
            asm volatile("global_load_dwordx4 %0, %1, off offset:64 sc0 sc1"  : "=v"(q1) : "v"(a0) : "memory");
            asm volatile("global_load_dwordx4 %0, %1, off offset:128 sc0 sc1" : "=v"(q2) : "v"(a0) : "memory");
            asm volatile("global_load_dwordx4 %0, %1, off offset:192 sc0 sc1" : "=v"(q3) : "v"(a0) : "memory");
            uint64_t a1 = xbase + HSTEP_BYTES;
            asm volatile("global_load_dwordx4 %0, %1, off sc0 sc1"            : "=v"(xA0) : "v"(a1) : "memory");
            asm volatile("global_load_dwordx4 %0, %1, off offset:64 sc0 sc1"  : "=v"(xA1) : "v"(a1) : "memory");
            asm volatile("global_load_dwordx4 %0, %1, off offset:128 sc0 sc1" : "=v"(xA2) : "v"(a1) : "memory");
            asm volatile("global_load_dwordx4 %0, %1, off offset:192 sc0 sc1" : "=v"(xA3) : "v"(a1) : "memory");
            vm_drain();
        }
        // acc_x(0) = bias + Wih1*h1(0)
        f32x4 acc_x[4];
#pragma unroll
        for (int nt = 0; nt < 4; ++nt) {
            f32x4 a = {biasv[nt], biasv[nt], biasv[nt], biasv[nt]};
            a = __builtin_amdgcn_mfma_f32_16x16x32_f16(q0, wih[nt][0], a, 0, 0, 0);
            a = __builtin_amdgcn_mfma_f32_16x16x32_f16(q1, wih[nt][1], a, 0, 0, 0);
            a = __builtin_amdgcn_mfma_f32_16x16x32_f16(q2, wih[nt][2], a, 0, 0, 0);
            a = __builtin_amdgcn_mfma_f32_16x16x32_f16(q3, wih[nt][3], a, 0, 0, 0);
            acc_x[nt] = a;
        }
        // async probe for cstep(0)'s flag check
        asm volatile("global_load_dword %0, %1, off sc0 sc1"
                     : "=v"(pv) : "v"(flagu) : "memory");

        float hlast[4] = {0.f, 0.f, 0.f, 0.f};

        auto cstep = [&](int t, f16x8& c0, f16x8& c1, f16x8& c2, f16x8& c3,
                         f16x8& n0, f16x8& n1, f16x8& n2, f16x8& n3) {
            const f16* cur = hbuf[t & 1];
            f16* nxt = hbuf[(t + 1) & 1];
            vm_drain();  // retires last step's 4 loads + probe (>=1 step old)
            if (t + 2 < T_SEQ) {
                unsigned need = (unsigned)(t + 3);
                if (pv < need) {
                    do {
                        asm volatile("global_load_dword %0, %1, off sc0 sc1"
                                     : "=v"(pv) : "v"(flagu) : "memory");
                        asm volatile("s_waitcnt vmcnt(0)" ::: "memory");
                    } while (pv < need);
                }
                uint64_t na = xbase + (uint64_t)(t + 2) * HSTEP_BYTES;
                asm volatile("global_load_dwordx4 %0, %1, off sc0 sc1"            : "=v"(n0) : "v"(na) : "memory");
                asm volatile("global_load_dwordx4 %0, %1, off offset:64 sc0 sc1"  : "=v"(n1) : "v"(na) : "memory");
                asm volatile("global_load_dwordx4 %0, %1, off offset:128 sc0 sc1" : "=v"(n2) : "v"(na) : "memory");
                asm volatile("global_load_dwordx4 %0, %1, off offset:192 sc0 sc1" : "=v"(n3) : "v"(na) : "memory");
                asm volatile("global_load_dword %0, %1, off sc0 sc1"
                             : "=v"(pv) : "v"(flagu) : "memory");
            }
            // path: ha reads + 4 dependent h-MFMAs from acc_x(t)
            f16x8 ha[4];
#pragma unroll
            for (int kc = 0; kc < 4; ++kc) {
                int chunk = kc * 4 + lg;
                ha[kc] = *(const f16x8*)(cur + l16 * HDIM + ((chunk ^ (l16 & 7)) << 3));
            }
            f32x4 acc[4];
#pragma unroll
            for (int nt = 0; nt < 4; ++nt) {
                f32x4 a = acc_x[nt];
                a = __builtin_amdgcn_mfma_f32_16x16x32_f16(ha[0], whh[nt][0], a, 0, 0, 0);
                a = __builtin_amdgcn_mfma_f32_16x16x32_f16(ha[1], whh[nt][1], a, 0, 0, 0);
                a = __builtin_amdgcn_mfma_f32_16x16x32_f16(ha[2], whh[nt][2], a, 0, 0, 0);
                a = __builtin_amdgcn_mfma_f32_16x16x32_f16(ha[3], whh[nt][3], a, 0, 0, 0);
                acc[nt] = a;
            }
            // shadow: acc_x(t+1) from h1(t+1) (prefetched 2 steps ago)
            if (t + 1 < T_SEQ) {
#pragma unroll
                for (int nt = 0; nt < 4; ++nt) {
                    f32x4 a = {biasv[nt], biasv[nt], biasv[nt], biasv[nt]};
                    a = __builtin_amdgcn_mfma_f32_16x16x32_f16(c0, wih[nt][0], a, 0, 0, 0);
                    a = __builtin_amdgcn_mfma_f32_16x16x32_f16(c1, wih[nt][1], a, 0, 0, 0);
                    a = __builtin_amdgcn_mfma_f32_16x16x32_f16(c2, wih[nt][2], a, 0, 0, 0);
                    a = __builtin_amdgcn_mfma_f32_16x16x32_f16(c3, wih[nt][3], a, 0, 0, 0);
                    acc_x[nt] = a;
                }
            }
            // activations -> h2(t)
#pragma unroll
            for (int r = 0; r < 4; ++r) {
                float iv = sigm(acc[0][r]);
                float fv = sigm(acc[1][r]);
                float gv = tanh_fast(acc[2][r]);
                float ov = sigm(acc[3][r]);
                float cn = fv * cst[r] + iv * gv;
                cst[r] = cn;
                float hv = ov * tanh_fast(cn);
                hlast[r] = hv;
                int br = lg * 4 + r;
                nxt[br * HDIM + ((((unsigned)u >> 3) ^ (br & 7)) << 3) + (u & 7)] = (f16)hv;
            }
            wg_barrier_lds();
        };

        f16x8 xB0, xB1, xB2, xB3;
        for (int t = 0; t < T_SEQ; t += 2) {
            cstep(t,     xA0, xA1, xA2, xA3, xB0, xB1, xB2, xB3);
            cstep(t + 1, xB0, xB1, xB2, xB3, xA0, xA1, xA2, xA3);
        }

        // ================= FC head on h2[:, T-1, :] =================
#pragma unroll
        for (int r = 0; r < 4; ++r) h2buf[lg * 4 + r][u] = hlast[r];
        __syncthreads();

        for (int i = tid; i < 16 * 64; i += 512) {
            int b = i >> 6, o = i & 63;
            float s = fc1b[o];
            for (int k = 0; k < HDIM; ++k) s += h2buf[b][k] * fc1w[o * HDIM + k];
            a1buf[b][o] = fmaxf(s, 0.f);
        }
        __syncthreads();
        if (tid < 16 * 32) {
            int b = tid >> 5, o = tid & 31;
            float s = fc2b[o];
            for (int k = 0; k < 64; ++k) s += a1buf[b][k] * fc2w[o * 64 + k];
            a2buf[b][o] = fmaxf(s, 0.f);
        }
        __syncthreads();
        if (tid < 32) {
            int b = tid >> 1, o = tid & 1;
            float s = fc3b[o];
            for (int k = 0; k < 32; ++k) s += a2buf[b][k] * fc3w[o * 32 + k];
            out[(wgb * B_TILE + b) * 2 + o] = s;
        }
    }
}

extern "C" void kernel_launch(void* const* d_in, const int* in_sizes, int n_in,
                              void* d_out, int out_size, void* d_ws, size_t ws_size,
                              hipStream_t stream)
{
    const float* x    = (const float*)d_in[0];
    const float* Wih0 = (const float*)d_in[1];
    const float* Whh0 = (const float*)d_in[2];
    const float* bih0 = (const float*)d_in[3];
    const float* bhh0 = (const float*)d_in[4];
    const float* Wih1 = (const float*)d_in[5];
    const float* Whh1 = (const float*)d_in[6];
    const float* bih1 = (const float*)d_in[7];
    const float* bhh1 = (const float*)d_in[8];
    const float* fc1w = (const float*)d_in[9];
    const float* fc1b = (const float*)d_in[10];
    const float* fc2w = (const float*)d_in[11];
    const float* fc2b = (const float*)d_in[12];
    const float* fc3w = (const float*)d_in[13];
    const float* fc3b = (const float*)d_in[14];

    f16* xT    = (f16*)d_ws;
    f16* h1    = (f16*)((char*)d_ws + XT_BYTES);
    int* flags = (int*)((char*)d_ws + FLAGS_OFF);

    // flags must be zero at the start of every launch (replays included)
    hipMemsetAsync(flags, 0, FLAGS_BYTES, stream);
    k_prep<<<B_ALL, 256, 0, stream>>>(x, xT);
    k_lstm<<<N_WG_TOT, 512, 0, stream>>>(xT, h1, flags, Wih0, Whh0, bih0, bhh0,
                                         Wih1, Whh1, bih1, bhh1,
                                         fc1w, fc1b, fc2w, fc2b, fc3w, fc3b,
                                         (float*)d_out);
}

// Round 9
// 383.002 us; speedup vs baseline: 6.7962x; 6.7962x over previous
//
#include <hip/hip_runtime.h>

// 2-layer LSTM (B=512, T=300, D=80, H=128) + FC head on MI355X.
// Round 9: r8 compute structure (gate split x-part/h-part) + r7 flag protocol.
//  - gates(t) = [bias + Wih*x(t)] (shadow, off-path) + [Whh*h(t-1)] (4 MFMAs, path)
//  - flags: per-(tile,step) 4B addresses (NO shared hot line), tid==0 publishes
//    AFTER the step barrier; producer uses counted vmcnt(4)/vmcnt(3) only.
//  - consumer: 2-deep LLC prefetch + early probe, one vm_drain/step.

typedef _Float16 f16;
typedef _Float16 f16x8 __attribute__((ext_vector_type(8)));
typedef float f32x4 __attribute__((ext_vector_type(4)));
typedef unsigned u32x2 __attribute__((ext_vector_type(2)));

#define T_SEQ 300
#define D_IN  80
#define HDIM  128
#define B_ALL 512
#define B_TILE 16
#define N_PROD 32
#define N_WG_TOT 64

#define XT_BYTES  ((size_t)B_ALL * T_SEQ * D_IN * 2)   // 24,576,000
#define H1_BYTES  ((size_t)T_SEQ * B_ALL * HDIM * 2)   // 39,321,600
#define FLAGS_OFF (XT_BYTES + H1_BYTES)
#define FLAGS_BYTES ((size_t)N_PROD * T_SEQ * 4)       // per (tile, step)
#define HSTEP_BYTES ((uint64_t)B_ALL * HDIM * 2)       // 131072

__device__ __forceinline__ float sigm(float x) {
    return __builtin_amdgcn_rcpf(1.0f + __builtin_amdgcn_exp2f(-1.44269504f * x));
}
__device__ __forceinline__ float tanh_fast(float x) {
    return 1.0f - 2.0f * __builtin_amdgcn_rcpf(1.0f + __builtin_amdgcn_exp2f(2.88539008f * x));
}

__device__ __forceinline__ void wg_barrier_lds() {
    asm volatile("s_waitcnt lgkmcnt(0)" ::: "memory");
    __builtin_amdgcn_sched_barrier(0);
    __builtin_amdgcn_s_barrier();
    __builtin_amdgcn_sched_barrier(0);
}
__device__ __forceinline__ void vm_drain() {
    asm volatile("s_waitcnt vmcnt(0)" ::: "memory");
    __builtin_amdgcn_sched_barrier(0);
}

// ---------------- prep: x (B,D,T) f32 -> xT (B,T,80) f16
__global__ __launch_bounds__(256) void k_prep(const float* __restrict__ x,
                                              f16* __restrict__ xT) {
    __shared__ f16 tile[D_IN][T_SEQ + 8];
    const int b = blockIdx.x;
    const int tid = threadIdx.x;
    const float* xb = x + (size_t)b * D_IN * T_SEQ;
    for (int i = tid; i < D_IN * T_SEQ; i += 256) {
        int d = i / T_SEQ;
        int t = i - d * T_SEQ;
        tile[d][t] = (f16)xb[i];
    }
    __syncthreads();
    f16* outb = xT + (size_t)b * T_SEQ * D_IN;
    for (int i = tid; i < T_SEQ * (D_IN / 8); i += 256) {
        int t  = i / (D_IN / 8);
        int dc = i - t * (D_IN / 8);
        f16x8 v;
#pragma unroll
        for (int e = 0; e < 8; ++e) v[e] = tile[dc * 8 + e][t];
        *(f16x8*)(outb + t * D_IN + dc * 8) = v;
    }
}

__device__ __forceinline__ f16x8 load_wfrag(const float* __restrict__ W,
                                            int row, int ld, int k0, int kmax) {
    f16x8 v;
#pragma unroll
    for (int e = 0; e < 8; ++e) {
        int k = k0 + e;
        v[e] = (k < kmax) ? (f16)W[row * ld + k] : (f16)0.0f;
    }
    return v;
}

__global__ __launch_bounds__(512, 2) void k_lstm(
    const f16* __restrict__ xT, f16* __restrict__ h1ws, int* __restrict__ flags,
    const float* __restrict__ Wih0, const float* __restrict__ Whh0,
    const float* __restrict__ bih0, const float* __restrict__ bhh0,
    const float* __restrict__ Wih1, const float* __restrict__ Whh1,
    const float* __restrict__ bih1, const float* __restrict__ bhh1,
    const float* __restrict__ fc1w, const float* __restrict__ fc1b,
    const float* __restrict__ fc2w, const float* __restrict__ fc2b,
    const float* __restrict__ fc3w, const float* __restrict__ fc3b,
    float* __restrict__ out)
{
    const int tid = threadIdx.x;
    const int wv  = tid >> 6;
    const int l   = tid & 63;
    const int l16 = l & 15;
    const int lg  = l >> 4;
    const int wg  = blockIdx.x;
    const int u   = wv * 16 + l16;

    __shared__ __align__(16) f16 hbuf[2][16 * HDIM];
    __shared__ float h2buf[16][HDIM];
    __shared__ float a1buf[16][64];
    __shared__ float a2buf[16][33];

    for (int i = tid; i < 16 * HDIM; i += 512) hbuf[0][i] = (f16)0.0f;

    float cst[4] = {0.f, 0.f, 0.f, 0.f};

    if (wg < N_PROD) {
        // ===================== PRODUCER: layer 0 =====================
        const int wgb = wg;
        f16x8 wih[4][3], whh[4][4];
        float biasv[4];
#pragma unroll
        for (int nt = 0; nt < 4; ++nt) {
            int gate = nt * 128 + u;
            biasv[nt] = bih0[gate] + bhh0[gate];
#pragma unroll
            for (int kc = 0; kc < 4; ++kc)
                whh[nt][kc] = load_wfrag(Whh0, gate, HDIM, kc * 32 + lg * 8, HDIM);
#pragma unroll
            for (int kc = 0; kc < 3; ++kc)
                wih[nt][kc] = load_wfrag(Wih0, gate, D_IN, kc * 32 + lg * 8, D_IN);
        }

        const f16* xrowp = xT + (size_t)(wgb * B_TILE + l16) * T_SEQ * D_IN + lg * 8;
        const uint64_t xrowu = (uint64_t)(uintptr_t)xrowp;
        const uint64_t flagu = (uint64_t)(uintptr_t)(flags + wgb * T_SEQ);
        // handoff-store geometry: thread -> (row sbr, 8 bytes at col-byte sob)
        const int sbr = tid >> 5;
        const int sob = (tid & 31) * 8;
        const int sswz = (((sob >> 4) ^ (sbr & 7)) << 4) + (sob & 8);
        const uint64_t sdst0 = (uint64_t)(uintptr_t)h1ws +
                               (uint64_t)(wgb * B_TILE + sbr) * 256 + sob;

        // prologue: plain loads of x(0), x(1); acc_x(0) = bias + Wih*x(0)
        f16x8 p0 = *(const f16x8*)(xrowp);
        f16x8 p1 = *(const f16x8*)(xrowp + 32);
        f16x8 p2 = *(const f16x8*)(xrowp + 64);
        f16x8 xA0 = *(const f16x8*)(xrowp + D_IN);
        f16x8 xA1 = *(const f16x8*)(xrowp + D_IN + 32);
        f16x8 xA2 = *(const f16x8*)(xrowp + D_IN + 64);
        f32x4 acc_x[4];
#pragma unroll
        for (int nt = 0; nt < 4; ++nt) {
            f32x4 a = {biasv[nt], biasv[nt], biasv[nt], biasv[nt]};
            a = __builtin_amdgcn_mfma_f32_16x16x32_f16(p0, wih[nt][0], a, 0, 0, 0);
            a = __builtin_amdgcn_mfma_f32_16x16x32_f16(p1, wih[nt][1], a, 0, 0, 0);
            a = __builtin_amdgcn_mfma_f32_16x16x32_f16(p2, wih[nt][2], a, 0, 0, 0);
            acc_x[nt] = a;
        }
        __syncthreads();  // hbuf[0] zeros visible

        auto pstep = [&](int t, f16x8& xc0, f16x8& xc1, f16x8& xc2,
                         f16x8& xn0, f16x8& xn1, f16x8& xn2) {
            const f16* cur = hbuf[t & 1];
            f16* nxt = hbuf[(t + 1) & 1];
            // ha reads first (latency head start)
            f16x8 ha[4];
#pragma unroll
            for (int kc = 0; kc < 4; ++kc) {
                int chunk = kc * 4 + lg;
                ha[kc] = *(const f16x8*)(cur + l16 * HDIM + ((chunk ^ (l16 & 7)) << 3));
            }
            // handoff store h(t-1) (coalesced 8B/lane from LDS)
            if (t >= 1) {
                u32x2 hval = *(const u32x2*)((const char*)cur + sbr * 256 + sswz);
                uint64_t dst = sdst0 + (uint64_t)(t - 1) * HSTEP_BYTES;
                asm volatile("global_store_dwordx2 %0, %1, off sc0 sc1"
                             :: "v"(dst), "v"(hval) : "memory");
            }
            // x loads for t+2 (plain, L2-cached)
            {
                int tl = (t + 2 < T_SEQ) ? t + 2 : T_SEQ - 1;
                uint64_t xa = xrowu + (uint64_t)tl * (D_IN * 2);
                asm volatile("global_load_dwordx4 %0, %1, off"            : "=v"(xn0) : "v"(xa) : "memory");
                asm volatile("global_load_dwordx4 %0, %1, off offset:64"  : "=v"(xn1) : "v"(xa) : "memory");
                asm volatile("global_load_dwordx4 %0, %1, off offset:128" : "=v"(xn2) : "v"(xa) : "memory");
            }
            // path: 4 dependent h-MFMAs per gate, C-init = acc_x(t)
            f32x4 acc[4];
#pragma unroll
            for (int nt = 0; nt < 4; ++nt) {
                f32x4 a = acc_x[nt];
                a = __builtin_amdgcn_mfma_f32_16x16x32_f16(ha[0], whh[nt][0], a, 0, 0, 0);
                a = __builtin_amdgcn_mfma_f32_16x16x32_f16(ha[1], whh[nt][1], a, 0, 0, 0);
                a = __builtin_amdgcn_mfma_f32_16x16x32_f16(ha[2], whh[nt][2], a, 0, 0, 0);
                a = __builtin_amdgcn_mfma_f32_16x16x32_f16(ha[3], whh[nt][3], a, 0, 0, 0);
                acc[nt] = a;
            }
            // guarantee x(t+1) loads (issued at t-1) landed.
            // youngest 4 ops per wave: hstore(t), xloads(t)x3; everything older
            // (incl. x(t+1) loads and wave0's flagstore(t-1)) retires at <=4.
            asm volatile("s_waitcnt vmcnt(4)" ::: "memory");
            __builtin_amdgcn_sched_barrier(0);
            // shadow: rebuild acc_x for t+1 (off-path MFMAs)
#pragma unroll
            for (int nt = 0; nt < 4; ++nt) {
                f32x4 a = {biasv[nt], biasv[nt], biasv[nt], biasv[nt]};
                a = __builtin_amdgcn_mfma_f32_16x16x32_f16(xc0, wih[nt][0], a, 0, 0, 0);
                a = __builtin_amdgcn_mfma_f32_16x16x32_f16(xc1, wih[nt][1], a, 0, 0, 0);
                a = __builtin_amdgcn_mfma_f32_16x16x32_f16(xc2, wih[nt][2], a, 0, 0, 0);
                acc_x[nt] = a;
            }
            // activations (on-path) -> h(t) into LDS
#pragma unroll
            for (int r = 0; r < 4; ++r) {
                float iv = sigm(acc[0][r]);
                float fv = sigm(acc[1][r]);
                float gv = tanh_fast(acc[2][r]);
                float ov = sigm(acc[3][r]);
                float cn = fv * cst[r] + iv * gv;
                cst[r] = cn;
                f16 hh = (f16)(ov * tanh_fast(cn));
                int br = lg * 4 + r;
                nxt[br * HDIM + ((((unsigned)u >> 3) ^ (br & 7)) << 3) + (u & 7)] = hh;
            }
            // own h-store retired (only 3 younger loads remain) -> barrier makes
            // it true for ALL waves -> tid==0 publishes flag[t-1].
            asm volatile("s_waitcnt vmcnt(3)" ::: "memory");
            __builtin_amdgcn_sched_barrier(0);
            wg_barrier_lds();
            if (tid == 0 && t >= 1) {
                unsigned one = 1;
                uint64_t fa = flagu + (uint64_t)(t - 1) * 4;
                asm volatile("global_store_dword %0, %1, off sc0 sc1"
                             :: "v"(fa), "v"(one) : "memory");
            }
        };

        f16x8 xB0, xB1, xB2;
        for (int t = 0; t < T_SEQ; t += 2) {
            pstep(t,     xA0, xA1, xA2, xB0, xB1, xB2);
            pstep(t + 1, xB0, xB1, xB2, xA0, xA1, xA2);
        }
        // tail: store h(T-1) (in hbuf[T&1]) and publish flag[T-1]
        {
            const f16* cur = hbuf[T_SEQ & 1];
            u32x2 hval = *(const u32x2*)((const char*)cur + sbr * 256 + sswz);
            uint64_t dst = sdst0 + (uint64_t)(T_SEQ - 1) * HSTEP_BYTES;
            asm volatile("global_store_dwordx2 %0, %1, off sc0 sc1"
                         :: "v"(dst), "v"(hval) : "memory");
            vm_drain();
            wg_barrier_lds();
            if (tid == 0) {
                unsigned one = 1;
                uint64_t fa = flagu + (uint64_t)(T_SEQ - 1) * 4;
                asm volatile("global_store_dword %0, %1, off sc0 sc1"
                             :: "v"(fa), "v"(one) : "memory");
            }
        }
        return;
    }

    // ===================== CONSUMER: layer 1 + FC =====================
    {
        const int wgb = wg - N_PROD;
        f16x8 wih[4][4], whh[4][4];
        float biasv[4];
#pragma unroll
        for (int nt = 0; nt < 4; ++nt) {
            int gate = nt * 128 + u;
            biasv[nt] = bih1[gate] + bhh1[gate];
#pragma unroll
            for (int kc = 0; kc < 4; ++kc) {
                wih[nt][kc] = load_wfrag(Wih1, gate, HDIM, kc * 32 + lg * 8, HDIM);
                whh[nt][kc] = load_wfrag(Whh1, gate, HDIM, kc * 32 + lg * 8, HDIM);
            }
        }
        __syncthreads();  // hbuf zeros visible

        const uint64_t flagu = (uint64_t)(uintptr_t)(flags + wgb * T_SEQ);
        const uint64_t xbase = (uint64_t)(uintptr_t)h1ws +
                               (uint64_t)(wgb * B_TILE + l16) * 256 + (uint64_t)lg * 16;

        // prologue: wait flag[0], flag[1]
        unsigned pv = 0;
#pragma unroll 1
        for (int s = 0; s < 2; ++s) {
            uint64_t fa = flagu + (uint64_t)s * 4;
            do {
                asm volatile("global_load_dword %0, %1, off sc0 sc1"
                             : "=v"(pv) : "v"(fa) : "memory");
                asm volatile("s_waitcnt vmcnt(0)" ::: "memory");
            } while (pv == 0);
        }
        // load h1(0) -> q, h1(1) -> xA
        f16x8 q0, q1, q2, q3, xA0, xA1, xA2, xA3;
        {
            uint64_t a0 = xbase;
            asm volatile("global_load_dwordx4 %0, %1, off sc0 sc1"            : "=v"(q0) : "v"(a0) : "memory");
            asm volatile("global_load_dwordx4 %0, %1, off offset:64 sc0 sc1"  : "=v"(q1) : "v"(a0) : "memory");
            asm volatile("global_load_dwordx4 %0, %1, off offset:128 sc0 sc1" : "=v"(q2) : "v"(a0) : "memory");
            asm volatile("global_load_dwordx4 %0, %1, off offset:192 sc0 sc1" : "=v"(q3) : "v"(a0) : "memory");
            uint64_t a1 = xbase + HSTEP_BYTES;
            asm volatile("global_load_dwordx4 %0, %1, off sc0 sc1"            : "=v"(xA0) : "v"(a1) : "memory");
            asm volatile("global_load_dwordx4 %0, %1, off offset:64 sc0 sc1"  : "=v"(xA1) : "v"(a1) : "memory");
            asm volatile("global_load_dwordx4 %0, %1, off offset:128 sc0 sc1" : "=v"(xA2) : "v"(a1) : "memory");
            asm volatile("global_load_dwordx4 %0, %1, off offset:192 sc0 sc1" : "=v"(xA3) : "v"(a1) : "memory");
            vm_drain();
        }
        // acc_x(0) = bias + Wih1*h1(0)
        f32x4 acc_x[4];
#pragma unroll
        for (int nt = 0; nt < 4; ++nt) {
            f32x4 a = {biasv[nt], biasv[nt], biasv[nt], biasv[nt]};
            a = __builtin_amdgcn_mfma_f32_16x16x32_f16(q0, wih[nt][0], a, 0, 0, 0);
            a = __builtin_amdgcn_mfma_f32_16x16x32_f16(q1, wih[nt][1], a, 0, 0, 0);
            a = __builtin_amdgcn_mfma_f32_16x16x32_f16(q2, wih[nt][2], a, 0, 0, 0);
            a = __builtin_amdgcn_mfma_f32_16x16x32_f16(q3, wih[nt][3], a, 0, 0, 0);
            acc_x[nt] = a;
        }
        // async probe of flag[2] for cstep(0)
        {
            uint64_t pf = flagu + 2 * 4;
            asm volatile("global_load_dword %0, %1, off sc0 sc1"
                         : "=v"(pv) : "v"(pf) : "memory");
        }

        float hlast[4] = {0.f, 0.f, 0.f, 0.f};

        auto cstep = [&](int t, f16x8& c0, f16x8& c1, f16x8& c2, f16x8& c3,
                         f16x8& n0, f16x8& n1, f16x8& n2, f16x8& n3) {
            const f16* cur = hbuf[t & 1];
            f16* nxt = hbuf[(t + 1) & 1];
            vm_drain();  // retires last step's 4 loads + probe (>=1 step old)
            if (t + 2 < T_SEQ) {
                if (pv == 0) {
                    uint64_t fa = flagu + (uint64_t)(t + 2) * 4;
                    do {
                        asm volatile("global_load_dword %0, %1, off sc0 sc1"
                                     : "=v"(pv) : "v"(fa) : "memory");
                        asm volatile("s_waitcnt vmcnt(0)" ::: "memory");
                    } while (pv == 0);
                }
                uint64_t na = xbase + (uint64_t)(t + 2) * HSTEP_BYTES;
                asm volatile("global_load_dwordx4 %0, %1, off sc0 sc1"            : "=v"(n0) : "v"(na) : "memory");
                asm volatile("global_load_dwordx4 %0, %1, off offset:64 sc0 sc1"  : "=v"(n1) : "v"(na) : "memory");
                asm volatile("global_load_dwordx4 %0, %1, off offset:128 sc0 sc1" : "=v"(n2) : "v"(na) : "memory");
                asm volatile("global_load_dwordx4 %0, %1, off offset:192 sc0 sc1" : "=v"(n3) : "v"(na) : "memory");
                if (t + 3 < T_SEQ) {
                    uint64_t pf = flagu + (uint64_t)(t + 3) * 4;
                    asm volatile("global_load_dword %0, %1, off sc0 sc1"
                                 : "=v"(pv) : "v"(pf) : "memory");
                }
            }
            // path: ha reads + 4 dependent h-MFMAs from acc_x(t)
            f16x8 ha[4];
#pragma unroll
            for (int kc = 0; kc < 4; ++kc) {
                int chunk = kc * 4 + lg;
                ha[kc] = *(const f16x8*)(cur + l16 * HDIM + ((chunk ^ (l16 & 7)) << 3));
            }
            f32x4 acc[4];
#pragma unroll
            for (int nt = 0; nt < 4; ++nt) {
                f32x4 a = acc_x[nt];
                a = __builtin_amdgcn_mfma_f32_16x16x32_f16(ha[0], whh[nt][0], a, 0, 0, 0);
                a = __builtin_amdgcn_mfma_f32_16x16x32_f16(ha[1], whh[nt][1], a, 0, 0, 0);
                a = __builtin_amdgcn_mfma_f32_16x16x32_f16(ha[2], whh[nt][2], a, 0, 0, 0);
                a = __builtin_amdgcn_mfma_f32_16x16x32_f16(ha[3], whh[nt][3], a, 0, 0, 0);
                acc[nt] = a;
            }
            // shadow: acc_x(t+1) from h1(t+1) (prefetched 2 steps ago)
            if (t + 1 < T_SEQ) {
#pragma unroll
                for (int nt = 0; nt < 4; ++nt) {
                    f32x4 a = {biasv[nt], biasv[nt], biasv[nt], biasv[nt]};
                    a = __builtin_amdgcn_mfma_f32_16x16x32_f16(c0, wih[nt][0], a, 0, 0, 0);
                    a = __builtin_amdgcn_mfma_f32_16x16x32_f16(c1, wih[nt][1], a, 0, 0, 0);
                    a = __builtin_amdgcn_mfma_f32_16x16x32_f16(c2, wih[nt][2], a, 0, 0, 0);
                    a = __builtin_amdgcn_mfma_f32_16x16x32_f16(c3, wih[nt][3], a, 0, 0, 0);
                    acc_x[nt] = a;
                }
            }
            // activations -> h2(t)
#pragma unroll
            for (int r = 0; r < 4; ++r) {
                float iv = sigm(acc[0][r]);
                float fv = sigm(acc[1][r]);
                float gv = tanh_fast(acc[2][r]);
                float ov = sigm(acc[3][r]);
                float cn = fv * cst[r] + iv * gv;
                cst[r] = cn;
                float hv = ov * tanh_fast(cn);
                hlast[r] = hv;
                int br = lg * 4 + r;
                nxt[br * HDIM + ((((unsigned)u >> 3) ^ (br & 7)) << 3) + (u & 7)] = (f16)hv;
            }
            wg_barrier_lds();
        };

        f16x8 xB0, xB1, xB2, xB3;
        for (int t = 0; t < T_SEQ; t += 2) {
            cstep(t,     xA0, xA1, xA2, xA3, xB0, xB1, xB2, xB3);
            cstep(t + 1, xB0, xB1, xB2, xB3, xA0, xA1, xA2, xA3);
        }

        // ================= FC head on h2[:, T-1, :] =================
#pragma unroll
        for (int r = 0; r < 4; ++r) h2buf[lg * 4 + r][u] = hlast[r];
        __syncthreads();

        for (int i = tid; i < 16 * 64; i += 512) {
            int b = i >> 6, o = i & 63;
            float s = fc1b[o];
            for (int k = 0; k < HDIM; ++k) s += h2buf[b][k] * fc1w[o * HDIM + k];
            a1buf[b][o] = fmaxf(s, 0.f);
        }
        __syncthreads();
        if (tid < 16 * 32) {
            int b = tid >> 5, o = tid & 31;
            float s = fc2b[o];
            for (int k = 0; k < 64; ++k) s += a1buf[b][k] * fc2w[o * 64 + k];
            a2buf[b][o] = fmaxf(s, 0.f);
        }
        __syncthreads();
        if (tid < 32) {
            int b = tid >> 1, o = tid & 1;
            float s = fc3b[o];
            for (int k = 0; k < 32; ++k) s += a2buf[b][k] * fc3w[o * 32 + k];
            out[(wgb * B_TILE + b) * 2 + o] = s;
        }
    }
}

extern "C" void kernel_launch(void* const* d_in, const int* in_sizes, int n_in,
                              void* d_out, int out_size, void* d_ws, size_t ws_size,
                              hipStream_t stream)
{
    const float* x    = (const float*)d_in[0];
    const float* Wih0 = (const float*)d_in[1];
    const float* Whh0 = (const float*)d_in[2];
    const float* bih0 = (const float*)d_in[3];
    const float* bhh0 = (const float*)d_in[4];
    const float* Wih1 = (const float*)d_in[5];
    const float* Whh1 = (const float*)d_in[6];
    const float* bih1 = (const float*)d_in[7];
    const float* bhh1 = (const float*)d_in[8];
    const float* fc1w = (const float*)d_in[9];
    const float* fc1b = (const float*)d_in[10];
    const float* fc2w = (const float*)d_in[11];
    const float* fc2b = (const float*)d_in[12];
    const float* fc3w = (const float*)d_in[13];
    const float* fc3b = (const float*)d_in[14];

    f16* xT    = (f16*)d_ws;
    f16* h1    = (f16*)((char*)d_ws + XT_BYTES);
    int* flags = (int*)((char*)d_ws + FLAGS_OFF);

    // flags must be zero at the start of every launch (replays included)
    hipMemsetAsync(flags, 0, FLAGS_BYTES, stream);
    k_prep<<<B_ALL, 256, 0, stream>>>(x, xT);
    k_lstm<<<N_WG_TOT, 512, 0, stream>>>(xT, h1, flags, Wih0, Whh0, bih0, bhh0,
                                         Wih1, Whh1, bih1, bhh1,
                                         fc1w, fc1b, fc2w, fc2b, fc3w, fc3b,
                                         (float*)d_out);
}

// Round 10
// 370.463 us; speedup vs baseline: 7.0262x; 1.0338x over previous
//
#include <hip/hip_runtime.h>

// 2-layer LSTM (B=512, T=300, D=80, H=128) + FC head on MI355X.
// Round 10: r9 protocol + (a) shadow-first MFMA order (hide ds_read latency),
// (b) 8-trans fused activation (5 exp2 + 3 rcp), (c) register-direct h1 stores
// during activation (drops the LDS->global handoff roundtrip), vmcnt(7) counted
// waits, flag published after barrier (per-wave store proof via pre-barrier wait).

typedef _Float16 f16;
typedef _Float16 f16x8 __attribute__((ext_vector_type(8)));
typedef float f32x4 __attribute__((ext_vector_type(4)));

#define T_SEQ 300
#define D_IN  80
#define HDIM  128
#define B_ALL 512
#define B_TILE 16
#define N_PROD 32
#define N_WG_TOT 64

#define XT_BYTES  ((size_t)B_ALL * T_SEQ * D_IN * 2)   // 24,576,000
#define H1_BYTES  ((size_t)T_SEQ * B_ALL * HDIM * 2)   // 39,321,600
#define FLAGS_OFF (XT_BYTES + H1_BYTES)
#define FLAGS_BYTES ((size_t)N_PROD * T_SEQ * 4)       // per (tile, step)
#define HSTEP_BYTES ((uint64_t)B_ALL * HDIM * 2)       // 131072

__device__ __forceinline__ void wg_barrier_lds() {
    asm volatile("s_waitcnt lgkmcnt(0)" ::: "memory");
    __builtin_amdgcn_sched_barrier(0);
    __builtin_amdgcn_s_barrier();
    __builtin_amdgcn_sched_barrier(0);
}
__device__ __forceinline__ void vm_drain() {
    asm volatile("s_waitcnt vmcnt(0)" ::: "memory");
    __builtin_amdgcn_sched_barrier(0);
}
__device__ __forceinline__ void vm_wait7() {
    asm volatile("s_waitcnt vmcnt(7)" ::: "memory");
    __builtin_amdgcn_sched_barrier(0);
}

// Fused LSTM pointwise: 5 exp2 + 3 rcp (was 10 trans).
//   i*tanh(g) = (Eg-1)/((1+Ei)(Eg+1)),  f = 1/(1+Ef)
//   c' = f*c + i*tanh(g);  h = o*tanh(c') = (Ec-1)/((1+Eo)(Ec+1))
__device__ __forceinline__ float lstm_fuse(float ai, float af, float ag, float ao,
                                           float& c) {
    float Ei = __builtin_amdgcn_exp2f(-1.44269504f * ai);
    float Ef = __builtin_amdgcn_exp2f(-1.44269504f * af);
    float Eo = __builtin_amdgcn_exp2f(-1.44269504f * ao);
    float Eg = __builtin_amdgcn_exp2f( 2.88539008f * ag);
    float ig = (Eg - 1.0f) * __builtin_amdgcn_rcpf((1.0f + Ei) * (Eg + 1.0f));
    float fs = __builtin_amdgcn_rcpf(1.0f + Ef);
    c = fs * c + ig;
    float Ec = __builtin_amdgcn_exp2f(2.88539008f * c);
    return (Ec - 1.0f) * __builtin_amdgcn_rcpf((1.0f + Eo) * (Ec + 1.0f));
}

// ---------------- prep: x (B,D,T) f32 -> xT (B,T,80) f16
__global__ __launch_bounds__(256) void k_prep(const float* __restrict__ x,
                                              f16* __restrict__ xT) {
    __shared__ f16 tile[D_IN][T_SEQ + 8];
    const int b = blockIdx.x;
    const int tid = threadIdx.x;
    const float* xb = x + (size_t)b * D_IN * T_SEQ;
    for (int i = tid; i < D_IN * T_SEQ; i += 256) {
        int d = i / T_SEQ;
        int t = i - d * T_SEQ;
        tile[d][t] = (f16)xb[i];
    }
    __syncthreads();
    f16* outb = xT + (size_t)b * T_SEQ * D_IN;
    for (int i = tid; i < T_SEQ * (D_IN / 8); i += 256) {
        int t  = i / (D_IN / 8);
        int dc = i - t * (D_IN / 8);
        f16x8 v;
#pragma unroll
        for (int e = 0; e < 8; ++e) v[e] = tile[dc * 8 + e][t];
        *(f16x8*)(outb + t * D_IN + dc * 8) = v;
    }
}

__device__ __forceinline__ f16x8 load_wfrag(const float* __restrict__ W,
                                            int row, int ld, int k0, int kmax) {
    f16x8 v;
#pragma unroll
    for (int e = 0; e < 8; ++e) {
        int k = k0 + e;
        v[e] = (k < kmax) ? (f16)W[row * ld + k] : (f16)0.0f;
    }
    return v;
}

__global__ __launch_bounds__(512, 2) void k_lstm(
    const f16* __restrict__ xT, f16* __restrict__ h1ws, int* __restrict__ flags,
    const float* __restrict__ Wih0, const float* __restrict__ Whh0,
    const float* __restrict__ bih0, const float* __restrict__ bhh0,
    const float* __restrict__ Wih1, const float* __restrict__ Whh1,
    const float* __restrict__ bih1, const float* __restrict__ bhh1,
    const float* __restrict__ fc1w, const float* __restrict__ fc1b,
    const float* __restrict__ fc2w, const float* __restrict__ fc2b,
    const float* __restrict__ fc3w, const float* __restrict__ fc3b,
    float* __restrict__ out)
{
    const int tid = threadIdx.x;
    const int wv  = tid >> 6;
    const int l   = tid & 63;
    const int l16 = l & 15;
    const int lg  = l >> 4;
    const int wg  = blockIdx.x;
    const int u   = wv * 16 + l16;

    __shared__ __align__(16) f16 hbuf[2][16 * HDIM];
    __shared__ float h2buf[16][HDIM];
    __shared__ float a1buf[16][64];
    __shared__ float a2buf[16][33];

    for (int i = tid; i < 16 * HDIM; i += 512) hbuf[0][i] = (f16)0.0f;

    float cst[4] = {0.f, 0.f, 0.f, 0.f};

    if (wg < N_PROD) {
        // ===================== PRODUCER: layer 0 =====================
        const int wgb = wg;
        f16x8 wih[4][3], whh[4][4];
        float biasv[4];
#pragma unroll
        for (int nt = 0; nt < 4; ++nt) {
            int gate = nt * 128 + u;
            biasv[nt] = bih0[gate] + bhh0[gate];
#pragma unroll
            for (int kc = 0; kc < 4; ++kc)
                whh[nt][kc] = load_wfrag(Whh0, gate, HDIM, kc * 32 + lg * 8, HDIM);
#pragma unroll
            for (int kc = 0; kc < 3; ++kc)
                wih[nt][kc] = load_wfrag(Wih0, gate, D_IN, kc * 32 + lg * 8, D_IN);
        }

        const uint64_t xrowu = (uint64_t)(uintptr_t)(
            xT + (size_t)(wgb * B_TILE + l16) * T_SEQ * D_IN + lg * 8);
        const uint64_t flagu = (uint64_t)(uintptr_t)(flags + wgb * T_SEQ);
        // register-direct h1 store: lane stores unit u, rows lg*4 + 0..3
        uint64_t haddr = (uint64_t)(uintptr_t)h1ws +
                         (uint64_t)(wgb * B_TILE + lg * 4) * 256 + (uint64_t)u * 2;

        // prologue (all-asm so loop vmcnt counts stay exact):
        // x(0) -> p, x(1) -> xA; drain; accA = bias + Wih*x(0)
        f16x8 p0, p1, p2, xA0, xA1, xA2, xB0, xB1, xB2;
        asm volatile("global_load_dwordx4 %0, %1, off"            : "=v"(p0)  : "v"(xrowu) : "memory");
        asm volatile("global_load_dwordx4 %0, %1, off offset:64"  : "=v"(p1)  : "v"(xrowu) : "memory");
        asm volatile("global_load_dwordx4 %0, %1, off offset:128" : "=v"(p2)  : "v"(xrowu) : "memory");
        {
            uint64_t xa = xrowu + (uint64_t)(D_IN * 2);
            asm volatile("global_load_dwordx4 %0, %1, off"            : "=v"(xA0) : "v"(xa) : "memory");
            asm volatile("global_load_dwordx4 %0, %1, off offset:64"  : "=v"(xA1) : "v"(xa) : "memory");
            asm volatile("global_load_dwordx4 %0, %1, off offset:128" : "=v"(xA2) : "v"(xa) : "memory");
        }
        vm_drain();
        f32x4 accA[4], accB[4];
#pragma unroll
        for (int nt = 0; nt < 4; ++nt) {
            f32x4 a = {biasv[nt], biasv[nt], biasv[nt], biasv[nt]};
            a = __builtin_amdgcn_mfma_f32_16x16x32_f16(p0, wih[nt][0], a, 0, 0, 0);
            a = __builtin_amdgcn_mfma_f32_16x16x32_f16(p1, wih[nt][1], a, 0, 0, 0);
            a = __builtin_amdgcn_mfma_f32_16x16x32_f16(p2, wih[nt][2], a, 0, 0, 0);
            accA[nt] = a;
        }
        __syncthreads();  // hbuf[0] zeros visible

        auto pstep = [&](int t, f16x8& xc0, f16x8& xc1, f16x8& xc2,
                         f16x8& xn0, f16x8& xn1, f16x8& xn2,
                         f32x4 (&accX)[4], f32x4 (&accN)[4]) {
            const f16* cur = hbuf[t & 1];
            f16* nxt = hbuf[(t + 1) & 1];
            // (1) ha ds_reads first (start latency earliest)
            f16x8 ha[4];
#pragma unroll
            for (int kc = 0; kc < 4; ++kc) {
                int chunk = kc * 4 + lg;
                ha[kc] = *(const f16x8*)(cur + l16 * HDIM + ((chunk ^ (l16 & 7)) << 3));
            }
            // (2) x loads for t+2
            {
                int tl = (t + 2 < T_SEQ) ? t + 2 : T_SEQ - 1;
                uint64_t xa = xrowu + (uint64_t)tl * (D_IN * 2);
                asm volatile("global_load_dwordx4 %0, %1, off"            : "=v"(xn0) : "v"(xa) : "memory");
                asm volatile("global_load_dwordx4 %0, %1, off offset:64"  : "=v"(xn1) : "v"(xa) : "memory");
                asm volatile("global_load_dwordx4 %0, %1, off offset:128" : "=v"(xn2) : "v"(xa) : "memory");
            }
            // (3) x(t+1) (in xc, loaded last step) proven landed:
            // queue old->new: x(t+1)x3, hst(t-1)x4, [flag(t-2) w0], x(t+2)x3
            vm_wait7();
            // (4) shadow: acc_x(t+1) — off h-path, hides ha ds latency
#pragma unroll
            for (int nt = 0; nt < 4; ++nt) {
                f32x4 a = {biasv[nt], biasv[nt], biasv[nt], biasv[nt]};
                a = __builtin_amdgcn_mfma_f32_16x16x32_f16(xc0, wih[nt][0], a, 0, 0, 0);
                a = __builtin_amdgcn_mfma_f32_16x16x32_f16(xc1, wih[nt][1], a, 0, 0, 0);
                a = __builtin_amdgcn_mfma_f32_16x16x32_f16(xc2, wih[nt][2], a, 0, 0, 0);
                accN[nt] = a;
            }
            // (5) path: 4 dependent h-MFMAs per gate, C-init = acc_x(t)
            f32x4 acc[4];
#pragma unroll
            for (int nt = 0; nt < 4; ++nt) {
                f32x4 a = accX[nt];
                a = __builtin_amdgcn_mfma_f32_16x16x32_f16(ha[0], whh[nt][0], a, 0, 0, 0);
                a = __builtin_amdgcn_mfma_f32_16x16x32_f16(ha[1], whh[nt][1], a, 0, 0, 0);
                a = __builtin_amdgcn_mfma_f32_16x16x32_f16(ha[2], whh[nt][2], a, 0, 0, 0);
                a = __builtin_amdgcn_mfma_f32_16x16x32_f16(ha[3], whh[nt][3], a, 0, 0, 0);
                acc[nt] = a;
            }
            // (6) activations + register-direct h1 stores + LDS exchange write
            unsigned hb[4];
#pragma unroll
            for (int r = 0; r < 4; ++r) {
                float hv = lstm_fuse(acc[0][r], acc[1][r], acc[2][r], acc[3][r], cst[r]);
                f16 hh = (f16)hv;
                hb[r] = (unsigned)__builtin_bit_cast(unsigned short, hh);
                int br = lg * 4 + r;
                nxt[br * HDIM + ((((unsigned)u >> 3) ^ (br & 7)) << 3) + (u & 7)] = hh;
            }
            asm volatile("global_store_short %0, %1, off sc0 sc1"            :: "v"(haddr), "v"(hb[0]) : "memory");
            asm volatile("global_store_short %0, %1, off offset:256 sc0 sc1" :: "v"(haddr), "v"(hb[1]) : "memory");
            asm volatile("global_store_short %0, %1, off offset:512 sc0 sc1" :: "v"(haddr), "v"(hb[2]) : "memory");
            asm volatile("global_store_short %0, %1, off offset:768 sc0 sc1" :: "v"(haddr), "v"(hb[3]) : "memory");
            haddr += HSTEP_BYTES;
            // (7) own hst(t-1) proven retired (queue: hst(t-1)#2-4, flag(t-2),
            // x(t+2)x3, hst(t)x4 -> vmcnt(7) retires all t-1 stores)
            vm_wait7();
            // (8) barrier: all waves' hst(t-1) proven -> publish flag[t-1]
            wg_barrier_lds();
            if (tid == 0 && t >= 1) {
                unsigned one = 1;
                uint64_t fa = flagu + (uint64_t)(t - 1) * 4;
                asm volatile("global_store_dword %0, %1, off sc0 sc1"
                             :: "v"(fa), "v"(one) : "memory");
            }
        };

        for (int t = 0; t < T_SEQ; t += 2) {
            pstep(t,     xA0, xA1, xA2, xB0, xB1, xB2, accA, accB);
            pstep(t + 1, xB0, xB1, xB2, xA0, xA1, xA2, accB, accA);
        }
        // tail: prove hst(T-1), publish flag[T-1]
        vm_drain();
        if (tid == 0) {
            unsigned one = 1;
            uint64_t fa = flagu + (uint64_t)(T_SEQ - 1) * 4;
            asm volatile("global_store_dword %0, %1, off sc0 sc1"
                         :: "v"(fa), "v"(one) : "memory");
        }
        return;
    }

    // ===================== CONSUMER: layer 1 + FC =====================
    {
        const int wgb = wg - N_PROD;
        f16x8 wih[4][4], whh[4][4];
        float biasv[4];
#pragma unroll
        for (int nt = 0; nt < 4; ++nt) {
            int gate = nt * 128 + u;
            biasv[nt] = bih1[gate] + bhh1[gate];
#pragma unroll
            for (int kc = 0; kc < 4; ++kc) {
                wih[nt][kc] = load_wfrag(Wih1, gate, HDIM, kc * 32 + lg * 8, HDIM);
                whh[nt][kc] = load_wfrag(Whh1, gate, HDIM, kc * 32 + lg * 8, HDIM);
            }
        }
        __syncthreads();  // hbuf zeros visible

        const uint64_t flagu = (uint64_t)(uintptr_t)(flags + wgb * T_SEQ);
        const uint64_t xbase = (uint64_t)(uintptr_t)h1ws +
                               (uint64_t)(wgb * B_TILE + l16) * 256 + (uint64_t)lg * 16;

        // prologue: wait flag[0], flag[1]
        unsigned pv = 0;
#pragma unroll 1
        for (int s = 0; s < 2; ++s) {
            uint64_t fa = flagu + (uint64_t)s * 4;
            do {
                asm volatile("global_load_dword %0, %1, off sc0 sc1"
                             : "=v"(pv) : "v"(fa) : "memory");
                asm volatile("s_waitcnt vmcnt(0)" ::: "memory");
            } while (pv == 0);
        }
        // load h1(0) -> q, h1(1) -> xA
        f16x8 q0, q1, q2, q3, xA0, xA1, xA2, xA3;
        {
            uint64_t a0 = xbase;
            asm volatile("global_load_dwordx4 %0, %1, off sc0 sc1"            : "=v"(q0) : "v"(a0) : "memory");
            asm volatile("global_load_dwordx4 %0, %1, off offset:64 sc0 sc1"  : "=v"(q1) : "v"(a0) : "memory");
            asm volatile("global_load_dwordx4 %0, %1, off offset:128 sc0 sc1" : "=v"(q2) : "v"(a0) : "memory");
            asm volatile("global_load_dwordx4 %0, %1, off offset:192 sc0 sc1" : "=v"(q3) : "v"(a0) : "memory");
            uint64_t a1 = xbase + HSTEP_BYTES;
            asm volatile("global_load_dwordx4 %0, %1, off sc0 sc1"            : "=v"(xA0) : "v"(a1) : "memory");
            asm volatile("global_load_dwordx4 %0, %1, off offset:64 sc0 sc1"  : "=v"(xA1) : "v"(a1) : "memory");
            asm volatile("global_load_dwordx4 %0, %1, off offset:128 sc0 sc1" : "=v"(xA2) : "v"(a1) : "memory");
            asm volatile("global_load_dwordx4 %0, %1, off offset:192 sc0 sc1" : "=v"(xA3) : "v"(a1) : "memory");
            vm_drain();
        }
        f32x4 accA[4], accB[4];
#pragma unroll
        for (int nt = 0; nt < 4; ++nt) {
            f32x4 a = {biasv[nt], biasv[nt], biasv[nt], biasv[nt]};
            a = __builtin_amdgcn_mfma_f32_16x16x32_f16(q0, wih[nt][0], a, 0, 0, 0);
            a = __builtin_amdgcn_mfma_f32_16x16x32_f16(q1, wih[nt][1], a, 0, 0, 0);
            a = __builtin_amdgcn_mfma_f32_16x16x32_f16(q2, wih[nt][2], a, 0, 0, 0);
            a = __builtin_amdgcn_mfma_f32_16x16x32_f16(q3, wih[nt][3], a, 0, 0, 0);
            accA[nt] = a;
        }
        // async probe of flag[2] for cstep(0)
        {
            uint64_t pf = flagu + 2 * 4;
            asm volatile("global_load_dword %0, %1, off sc0 sc1"
                         : "=v"(pv) : "v"(pf) : "memory");
        }

        float hlast[4] = {0.f, 0.f, 0.f, 0.f};

        auto cstep = [&](int t, f16x8& c0, f16x8& c1, f16x8& c2, f16x8& c3,
                         f16x8& n0, f16x8& n1, f16x8& n2, f16x8& n3,
                         f32x4 (&accX)[4], f32x4 (&accN)[4]) {
            const f16* cur = hbuf[t & 1];
            f16* nxt = hbuf[(t + 1) & 1];
            // (1) ha ds_reads first
            f16x8 ha[4];
#pragma unroll
            for (int kc = 0; kc < 4; ++kc) {
                int chunk = kc * 4 + lg;
                ha[kc] = *(const f16x8*)(cur + l16 * HDIM + ((chunk ^ (l16 & 7)) << 3));
            }
            // (2) retire last step's loads+probe (>=1 step old, free) -> pv valid
            vm_drain();
            if (t + 2 < T_SEQ) {
                if (pv == 0) {
                    uint64_t fa = flagu + (uint64_t)(t + 2) * 4;
                    do {
                        asm volatile("global_load_dword %0, %1, off sc0 sc1"
                                     : "=v"(pv) : "v"(fa) : "memory");
                        asm volatile("s_waitcnt vmcnt(0)" ::: "memory");
                    } while (pv == 0);
                }
                uint64_t na = xbase + (uint64_t)(t + 2) * HSTEP_BYTES;
                asm volatile("global_load_dwordx4 %0, %1, off sc0 sc1"            : "=v"(n0) : "v"(na) : "memory");
                asm volatile("global_load_dwordx4 %0, %1, off offset:64 sc0 sc1"  : "=v"(n1) : "v"(na) : "memory");
                asm volatile("global_load_dwordx4 %0, %1, off offset:128 sc0 sc1" : "=v"(n2) : "v"(na) : "memory");
                asm volatile("global_load_dwordx4 %0, %1, off offset:192 sc0 sc1" : "=v"(n3) : "v"(na) : "memory");
                if (t + 3 < T_SEQ) {
                    uint64_t pf = flagu + (uint64_t)(t + 3) * 4;
                    asm volatile("global_load_dword %0, %1, off sc0 sc1"
                                 : "=v"(pv) : "v"(pf) : "memory");
                }
            }
            // (3) shadow: acc_x(t+1) from h1(t+1) — hides ha ds latency
            if (t + 1 < T_SEQ) {
#pragma unroll
                for (int nt = 0; nt < 4; ++nt) {
                    f32x4 a = {biasv[nt], biasv[nt], biasv[nt], biasv[nt]};
                    a = __builtin_amdgcn_mfma_f32_16x16x32_f16(c0, wih[nt][0], a, 0, 0, 0);
                    a = __builtin_amdgcn_mfma_f32_16x16x32_f16(c1, wih[nt][1], a, 0, 0, 0);
                    a = __builtin_amdgcn_mfma_f32_16x16x32_f16(c2, wih[nt][2], a, 0, 0, 0);
                    a = __builtin_amdgcn_mfma_f32_16x16x32_f16(c3, wih[nt][3], a, 0, 0, 0);
                    accN[nt] = a;
                }
            }
            // (4) path
            f32x4 acc[4];
#pragma unroll
            for (int nt = 0; nt < 4; ++nt) {
                f32x4 a = accX[nt];
                a = __builtin_amdgcn_mfma_f32_16x16x32_f16(ha[0], whh[nt][0], a, 0, 0, 0);
                a = __builtin_amdgcn_mfma_f32_16x16x32_f16(ha[1], whh[nt][1], a, 0, 0, 0);
                a = __builtin_amdgcn_mfma_f32_16x16x32_f16(ha[2], whh[nt][2], a, 0, 0, 0);
                a = __builtin_amdgcn_mfma_f32_16x16x32_f16(ha[3], whh[nt][3], a, 0, 0, 0);
                acc[nt] = a;
            }
            // (5) activations -> h2(t)
#pragma unroll
            for (int r = 0; r < 4; ++r) {
                float hv = lstm_fuse(acc[0][r], acc[1][r], acc[2][r], acc[3][r], cst[r]);
                hlast[r] = hv;
                int br = lg * 4 + r;
                nxt[br * HDIM + ((((unsigned)u >> 3) ^ (br & 7)) << 3) + (u & 7)] = (f16)hv;
            }
            wg_barrier_lds();
        };

        f16x8 xB0, xB1, xB2, xB3;
        for (int t = 0; t < T_SEQ; t += 2) {
            cstep(t,     xA0, xA1, xA2, xA3, xB0, xB1, xB2, xB3, accA, accB);
            cstep(t + 1, xB0, xB1, xB2, xB3, xA0, xA1, xA2, xA3, accB, accA);
        }

        // ================= FC head on h2[:, T-1, :] =================
#pragma unroll
        for (int r = 0; r < 4; ++r) h2buf[lg * 4 + r][u] = hlast[r];
        __syncthreads();

        for (int i = tid; i < 16 * 64; i += 512) {
            int b = i >> 6, o = i & 63;
            float s = fc1b[o];
            for (int k = 0; k < HDIM; ++k) s += h2buf[b][k] * fc1w[o * HDIM + k];
            a1buf[b][o] = fmaxf(s, 0.f);
        }
        __syncthreads();
        if (tid < 16 * 32) {
            int b = tid >> 5, o = tid & 31;
            float s = fc2b[o];
            for (int k = 0; k < 64; ++k) s += a1buf[b][k] * fc2w[o * 64 + k];
            a2buf[b][o] = fmaxf(s, 0.f);
        }
        __syncthreads();
        if (tid < 32) {
            int b = tid >> 1, o = tid & 1;
            float s = fc3b[o];
            for (int k = 0; k < 32; ++k) s += a2buf[b][k] * fc3w[o * 32 + k];
            out[(wgb * B_TILE + b) * 2 + o] = s;
        }
    }
}

extern "C" void kernel_launch(void* const* d_in, const int* in_sizes, int n_in,
                              void* d_out, int out_size, void* d_ws, size_t ws_size,
                              hipStream_t stream)
{
    const float* x    = (const float*)d_in[0];
    const float* Wih0 = (const float*)d_in[1];
    const float* Whh0 = (const float*)d_in[2];
    const float* bih0 = (const float*)d_in[3];
    const float* bhh0 = (const float*)d_in[4];
    const float* Wih1 = (const float*)d_in[5];
    const float* Whh1 = (const float*)d_in[6];
    const float* bih1 = (const float*)d_in[7];
    const float* bhh1 = (const float*)d_in[8];
    const float* fc1w = (const float*)d_in[9];
    const float* fc1b = (const float*)d_in[10];
    const float* fc2w = (const float*)d_in[11];
    const float* fc2b = (const float*)d_in[12];
    const float* fc3w = (const float*)d_in[13];
    const float* fc3b = (const float*)d_in[14];

    f16* xT    = (f16*)d_ws;
    f16* h1    = (f16*)((char*)d_ws + XT_BYTES);
    int* flags = (int*)((char*)d_ws + FLAGS_OFF);

    // flags must be zero at the start of every launch (replays included)
    hipMemsetAsync(flags, 0, FLAGS_BYTES, stream);
    k_prep<<<B_ALL, 256, 0, stream>>>(x, xT);
    k_lstm<<<N_WG_TOT, 512, 0, stream>>>(xT, h1, flags, Wih0, Whh0, bih0, bhh0,
                                         Wih1, Whh1, bih1, bhh1,
                                         fc1w, fc1b, fc2w, fc2b, fc3w, fc3b,
                                         (float*)d_out);
}